// Round 2
// baseline (72.346 us; speedup 1.0000x reference)
//
#include <hip/hip_runtime.h>

// QuantumCircuit 16q/4layers/batch512 via EXACT MPS (bond dim 16),
// meet-in-the-middle sweep, REGISTER/SHUFFLE dataflow (no sweep barriers).
//
// Math identical to the verified R1 kernel:
//   Lam'_j = sum_c W_{j^c}^dag Lam_c W_{j^c}   (per env; right env uses the
//   index-swapped site tensor). Factored per step as
//     stage1: P_{c,m} = Lam_c * W_m          (4 products / env)
//     stage2: Lam'_0 = W_0^dag P_{0,0} + W_1^dag P_{1,1}
//             Lam'_1 = W_1^dag P_{0,1} + W_0^dag P_{1,0}
//   Base L: Lam_c = z_c conj(B0[c,:]) B0[c,:]^T;  base R: r15 r15^dag (both blocks).
//   Merge: M = Re sum_c <LamL_c, LamR_c>.
//
// Layout: lane (i = t>>3, j = t&7) owns element [i][j] of every 8x8 matrix.
// Cross-lane operand motion inside a matmul is ds_bpermute (one op replaces
// the old ds_write -> s_waitcnt -> s_barrier -> ds_read chain). Site tensors
// W live in read-only LDS (built once, 1 barrier), preloaded per step as
// lane-local columns: wc[slot][m][col][k] with col stride 10 float2 (80 B,
// 16B-aligned, 8 distinct cols hit 32 distinct banks -> conflict-free b128).
// Barriers: 2 (setup only). Sweep: 7 steps of pure VALU+bpermute dataflow.

#define NQ 16

__device__ __forceinline__ float2 cmul(float2 a, float2 b){
    return make_float2(a.x*b.x - a.y*b.y, a.x*b.y + a.y*b.x);
}
__device__ __forceinline__ float2 cmulc(float2 a, float2 b){   // conj(a)*b
    return make_float2(a.x*b.x + a.y*b.y, a.x*b.y - a.y*b.x);
}
__device__ __forceinline__ void cfma(float2& acc, float2 a, float2 b){      // acc += a*b
    acc.x = fmaf(a.x, b.x, fmaf(-a.y, b.y, acc.x));
    acc.y = fmaf(a.x, b.y, fmaf( a.y, b.x, acc.y));
}
__device__ __forceinline__ void cfmac(float2& acc, float2 a, float2 b){     // acc += conj(a)*b
    acc.x = fmaf(a.x, b.x, fmaf( a.y, b.y, acc.x));
    acc.y = fmaf(a.x, b.y, fmaf(-a.y, b.x, acc.y));
}
__device__ __forceinline__ float2 shfl2(float2 v, int bidx){   // bidx = srclane*4
    int x = __builtin_amdgcn_ds_bpermute(bidx, __float_as_int(v.x));
    int y = __builtin_amdgcn_ds_bpermute(bidx, __float_as_int(v.y));
    return make_float2(__int_as_float(x), __int_as_float(y));
}

// Rot(phi,theta,omega) = RZ(omega) RY(theta) RZ(phi)
__device__ __forceinline__ void make_rot(const float* __restrict__ params, int L, int q, float u[8]){
    const float* pp = params + (L*NQ + q)*3;
    float phi = pp[0], th = pp[1], om = pp[2];
    float s, c;     sincosf(0.5f*th, &s, &c);
    float sap, cap; sincosf(0.5f*(phi+om), &sap, &cap);
    float sam, cam; sincosf(0.5f*(phi-om), &sam, &cam);
    u[0] =  c*cap; u[1] = -c*sap;
    u[2] = -s*cam; u[3] = -s*sam;
    u[4] =  s*cam; u[5] = -s*sam;
    u[6] =  c*cap; u[7] =  c*sap;
}
__device__ __forceinline__ void fuse_ry(float a, float u[8]){
    float sa, ca; sincosf(0.5f*a, &sa, &ca);
    float f0r =  u[0]*ca + u[2]*sa, f0i =  u[1]*ca + u[3]*sa;
    float f1r = -u[0]*sa + u[2]*ca, f1i = -u[1]*sa + u[3]*ca;
    float g0r =  u[4]*ca + u[6]*sa, g0i =  u[5]*ca + u[7]*sa;
    float g1r = -u[4]*sa + u[6]*ca, g1i = -u[5]*sa + u[7]*ca;
    u[0]=f0r; u[1]=f0i; u[2]=f1r; u[3]=f1i; u[4]=g0r; u[5]=g0i; u[6]=g1r; u[7]=g1i;
}

// load one 8-complex column (16B-aligned, contiguous) into registers
__device__ __forceinline__ void load_col(const float2* __restrict__ p, float2 dst[8]){
    const float4* q = (const float4*)p;
    #pragma unroll
    for (int h = 0; h < 4; ++h) {
        float4 f = q[h];
        dst[2*h]   = make_float2(f.x, f.y);
        dst[2*h+1] = make_float2(f.z, f.w);
    }
}

__launch_bounds__(64)
__global__ void qmps_kernel(const float* __restrict__ inputs,
                            const float* __restrict__ params,
                            float* __restrict__ out)
{
    __shared__ __align__(16) float2 U[3][NQ][2][2];     // U[l][q] = Rot(params[l+1,q])
    __shared__ __align__(16) float2 v[NQ][2];           // Rot(params[0,q])*RY(x_q)|0>
    __shared__ __align__(16) float2 wc[14][2][8][10];   // wc[slot][m][col][k] = W_m[k][col]
    __shared__ __align__(16) float2 B0s[2][8];
    __shared__ __align__(16) float2 r15s[8][2];

    const int t = threadIdx.x;            // one wave
    const int b = blockIdx.x;             // batch element

    // ---- phase 0: gate matrices + init vectors ----
    if (t < 48) {
        int l = t >> 4, q = t & 15;
        float u[8]; make_rot(params, l+1, q, u);
        U[l][q][0][0] = make_float2(u[0],u[1]); U[l][q][0][1] = make_float2(u[2],u[3]);
        U[l][q][1][0] = make_float2(u[4],u[5]); U[l][q][1][1] = make_float2(u[6],u[7]);
    } else {
        int q = t - 48;
        float u[8]; make_rot(params, 0, q, u);
        fuse_ry(inputs[b*NQ + q], u);
        v[q][0] = make_float2(u[0],u[1]);
        v[q][1] = make_float2(u[4],u[5]);
    }
    __syncthreads();

    // ---- phase 1: site tensors into wc + edge vectors ----
    // wc[ws][m][beta][alpha] = r3_eff[alpha][m][beta] (right slots index-swapped),
    // i.e. exactly W_m[k=alpha][col=beta] for that slot's env.
    #pragma unroll 4
    for (int kk = 0; kk < 28; ++kk) {
        int e     = t + (kk << 6);
        int ws    = e >> 7;               // 0..13
        int idx   = e & 127;
        int alpha = idx & 7, beta = (idx >> 3) & 7, m = (idx >> 6) & 1;
        int site  = ws + 1;               // 1..14
        int uu = (site <= 7) ? alpha : beta;    // left-bond bits (c1..c3)
        int dd = (site <= 7) ? beta  : alpha;   // right-bond bits (d1..d3)
        int c1 = uu & 1, c2 = (uu >> 1) & 1, c3 = (uu >> 2) & 1;
        int d1 = dd & 1, d2 = (dd >> 1) & 1, d3 = (dd >> 2) & 1;
        float2 val = cmul(U[2][site][m][d3],
                     cmul(U[1][site][d3^c3][d2],
                     cmul(U[0][site][d2^c2][d1], v[site][d1^c1])));
        wc[ws][m][beta][alpha] = val;
    }
    if (t < 16) {
        // site 0: B0[j][ap] = U3[j,d3] U2[d3,d2] U1[d2,d1] v[d1]
        int jj = t >> 3, ap = t & 7;
        int d1 = ap & 1, d2 = (ap>>1)&1, d3 = (ap>>2)&1;
        B0s[jj][ap] = cmul(U[2][0][jj][d3],
                      cmul(U[1][0][d3][d2],
                      cmul(U[0][0][d2][d1], v[0][d1])));
    } else if (t < 32) {
        // site 15: r15[a][k] = sum_s U3[k,s3] U2[s3^c3,s2] U1[s2^c2,s1] v[s1^c1]
        int t2 = t - 16;
        int a = t2 >> 1, k = t2 & 1;
        int c1 = a & 1, c2 = (a>>1)&1, c3 = (a>>2)&1;
        float2 in1[2], in2[2];
        #pragma unroll
        for (int s2 = 0; s2 < 2; ++s2) {
            float2 acc = make_float2(0.f, 0.f);
            #pragma unroll
            for (int s1 = 0; s1 < 2; ++s1) cfma(acc, U[0][15][s2^c2][s1], v[15][s1^c1]);
            in1[s2] = acc;
        }
        #pragma unroll
        for (int s3 = 0; s3 < 2; ++s3) {
            float2 acc = make_float2(0.f, 0.f);
            #pragma unroll
            for (int s2 = 0; s2 < 2; ++s2) cfma(acc, U[1][15][s3^c3][s2], in1[s2]);
            in2[s3] = acc;
        }
        float2 acc = make_float2(0.f, 0.f);
        #pragma unroll
        for (int s3 = 0; s3 < 2; ++s3) cfma(acc, U[2][15][k][s3], in2[s3]);
        r15s[a][k] = acc;
    }
    __syncthreads();                      // LAST barrier — sweep is barrier-free

    const int i = t >> 3, j = t & 7;      // lane owns element [i][j]
    // ---- env init in registers ----
    float2 LamL0, LamL1, LamR0, LamR1;
    {
        LamL0 = cmulc(B0s[0][i], B0s[0][j]);
        float2 l1 = cmulc(B0s[1][i], B0s[1][j]);
        LamL1 = make_float2(-l1.x, -l1.y);              // z_1 = -1
        float2 r = cmulc(r15s[i][0], r15s[j][0]);
        cfmac(r, r15s[i][1], r15s[j][1]);
        LamR0 = r; LamR1 = r;                           // c-independent base
    }

    const int iA0 = (t << 2) & 0xE0;      // ((t & 0x38))*4 : row-broadcast base
    const int jB0 = (t & 7) << 2;         // (j)*4          : col-gather base

    #pragma unroll 1                      // keep body ~6.5 KB: fits I-cache
    for (int st = 0; st < 7; ++st) {
        const int sL = st, sR = 13 - st;
        // preload site-tensor columns (read-only LDS, conflict-free, b128)
        float2 W1L[2][8], W2L[2][8], W1R[2][8], W2R[2][8];
        #pragma unroll
        for (int m = 0; m < 2; ++m) {
            load_col(&wc[sL][m][j][0], W1L[m]);   // W_m[k][j]  (stage-1 B-op)
            load_col(&wc[sL][m][i][0], W2L[m]);   // W_m[k][i]  (stage-2 A-op)
            load_col(&wc[sR][m][j][0], W1R[m]);
            load_col(&wc[sR][m][i][0], W2R[m]);
        }
        // ---- stage 1: P_{c,m}[i][j] = sum_k Lam_c[i][k] * W_m[k][j] ----
        float2 PL00 = make_float2(0.f,0.f), PL01 = make_float2(0.f,0.f);
        float2 PL10 = make_float2(0.f,0.f), PL11 = make_float2(0.f,0.f);
        float2 PR00 = make_float2(0.f,0.f), PR01 = make_float2(0.f,0.f);
        float2 PR10 = make_float2(0.f,0.f), PR11 = make_float2(0.f,0.f);
        #pragma unroll
        for (int k = 0; k < 8; ++k) {
            const int iA = iA0 | (k << 2);        // src lane (i<<3)|k
            float2 a0 = shfl2(LamL0, iA);
            float2 a1 = shfl2(LamL1, iA);
            float2 b0 = shfl2(LamR0, iA);
            float2 b1 = shfl2(LamR1, iA);
            cfma(PL00, a0, W1L[0][k]); cfma(PL01, a0, W1L[1][k]);
            cfma(PL10, a1, W1L[0][k]); cfma(PL11, a1, W1L[1][k]);
            cfma(PR00, b0, W1R[0][k]); cfma(PR01, b0, W1R[1][k]);
            cfma(PR10, b1, W1R[0][k]); cfma(PR11, b1, W1R[1][k]);
        }
        // ---- stage 2: Lam'_0 = W0^dag P00 + W1^dag P11 ; Lam'_1 = W1^dag P01 + W0^dag P10 ----
        float2 nL0 = make_float2(0.f,0.f), nL1 = make_float2(0.f,0.f);
        float2 nR0 = make_float2(0.f,0.f), nR1 = make_float2(0.f,0.f);
        #pragma unroll
        for (int k = 0; k < 8; ++k) {
            const int iB = jB0 | (k << 5);        // src lane (k<<3)|j
            float2 p00 = shfl2(PL00, iB);
            float2 p01 = shfl2(PL01, iB);
            float2 p10 = shfl2(PL10, iB);
            float2 p11 = shfl2(PL11, iB);
            cfmac(nL0, W2L[0][k], p00); cfmac(nL0, W2L[1][k], p11);
            cfmac(nL1, W2L[1][k], p01); cfmac(nL1, W2L[0][k], p10);
            float2 q00 = shfl2(PR00, iB);
            float2 q01 = shfl2(PR01, iB);
            float2 q10 = shfl2(PR10, iB);
            float2 q11 = shfl2(PR11, iB);
            cfmac(nR0, W2R[0][k], q00); cfmac(nR0, W2R[1][k], q11);
            cfmac(nR1, W2R[1][k], q01); cfmac(nR1, W2R[0][k], q10);
        }
        LamL0 = nL0; LamL1 = nL1; LamR0 = nR0; LamR1 = nR1;
    }

    // ---- merge: M = Re sum_c <LamL_c, LamR_c> — lane-local then reduce ----
    float m = LamL0.x*LamR0.x - LamL0.y*LamR0.y
            + LamL1.x*LamR1.x - LamL1.y*LamR1.y;
    #pragma unroll
    for (int off = 32; off > 0; off >>= 1) m += __shfl_down(m, off, 64);
    if (t == 0) out[b] = m;
}

extern "C" void kernel_launch(void* const* d_in, const int* in_sizes, int n_in,
                              void* d_out, int out_size, void* d_ws, size_t ws_size,
                              hipStream_t stream) {
    (void)n_in; (void)out_size; (void)d_ws; (void)ws_size;
    const float* inputs = (const float*)d_in[0];   // (B,16) f32
    const float* params = (const float*)d_in[1];   // (4,16,3) f32
    float* out = (float*)d_out;                    // (B,) f32
    const int B = in_sizes[0] / NQ;
    qmps_kernel<<<B, 64, 0, stream>>>(inputs, params, out);
}

// Round 3
// 68.263 us; speedup vs baseline: 1.0598x; 1.0598x over previous
//
#include <hip/hip_runtime.h>

// QuantumCircuit 16q/4layers/batch512 via EXACT MPS (bond dim 16),
// meet-in-the-middle sweep, TWO-WAVE split: wave0 evolves the LEFT
// environment, wave1 the RIGHT (they are independent until the final
// trace), register/shuffle dataflow inside each wave.
//
// Math identical to the verified R2 kernel:
//   per step (per env): Lam'_j = sum_c W_{j^c}^dag Lam_c W_{j^c}
//     stage1: P_{c,m} = Lam_c * W_m
//     stage2: Lam'_0 = W_0^dag P_00 + W_1^dag P_11
//             Lam'_1 = W_1^dag P_01 + W_0^dag P_10
//   Base L: Lam_c = z_c conj(B0[c,:]) B0[c,:]^T ; base R: r15 r15^dag (both
//   blocks). Merge: M = Re sum_c sum_ij LamL_c[i][j] * LamR_c[i][j].
//
// Layout: lane (i=lane>>3, j=lane&7) owns element [i][j] of its wave's
// matrices. Cross-lane motion = ds_bpermute (wave64-wide on CDNA).
// Site tensors in read-only LDS, columns contiguous (pad 10 float2 ->
// b128, conflict-free). Barriers: 3 total. Per wave per step:
// 48 shfl2 + 64 cfma + 16 ds_read_b128 — half of R2's per-step cost.

#define NQ 16

__device__ __forceinline__ float2 cmul(float2 a, float2 b){
    return make_float2(a.x*b.x - a.y*b.y, a.x*b.y + a.y*b.x);
}
__device__ __forceinline__ float2 cmulc(float2 a, float2 b){   // conj(a)*b
    return make_float2(a.x*b.x + a.y*b.y, a.x*b.y - a.y*b.x);
}
__device__ __forceinline__ void cfma(float2& acc, float2 a, float2 b){      // acc += a*b
    acc.x = fmaf(a.x, b.x, fmaf(-a.y, b.y, acc.x));
    acc.y = fmaf(a.x, b.y, fmaf( a.y, b.x, acc.y));
}
__device__ __forceinline__ void cfmac(float2& acc, float2 a, float2 b){     // acc += conj(a)*b
    acc.x = fmaf(a.x, b.x, fmaf( a.y, b.y, acc.x));
    acc.y = fmaf(a.x, b.y, fmaf(-a.y, b.x, acc.y));
}
__device__ __forceinline__ float2 shfl2(float2 v, int bidx){   // bidx = srclane*4
    int x = __builtin_amdgcn_ds_bpermute(bidx, __float_as_int(v.x));
    int y = __builtin_amdgcn_ds_bpermute(bidx, __float_as_int(v.y));
    return make_float2(__int_as_float(x), __int_as_float(y));
}

// Rot(phi,theta,omega) = RZ(omega) RY(theta) RZ(phi)
__device__ __forceinline__ void make_rot(const float* __restrict__ params, int L, int q, float u[8]){
    const float* pp = params + (L*NQ + q)*3;
    float phi = pp[0], th = pp[1], om = pp[2];
    float s, c;     sincosf(0.5f*th, &s, &c);
    float sap, cap; sincosf(0.5f*(phi+om), &sap, &cap);
    float sam, cam; sincosf(0.5f*(phi-om), &sam, &cam);
    u[0] =  c*cap; u[1] = -c*sap;
    u[2] = -s*cam; u[3] = -s*sam;
    u[4] =  s*cam; u[5] = -s*sam;
    u[6] =  c*cap; u[7] =  c*sap;
}
__device__ __forceinline__ void fuse_ry(float a, float u[8]){
    float sa, ca; sincosf(0.5f*a, &sa, &ca);
    float f0r =  u[0]*ca + u[2]*sa, f0i =  u[1]*ca + u[3]*sa;
    float f1r = -u[0]*sa + u[2]*ca, f1i = -u[1]*sa + u[3]*ca;
    float g0r =  u[4]*ca + u[6]*sa, g0i =  u[5]*ca + u[7]*sa;
    float g1r = -u[4]*sa + u[6]*ca, g1i = -u[5]*sa + u[7]*ca;
    u[0]=f0r; u[1]=f0i; u[2]=f1r; u[3]=f1i; u[4]=g0r; u[5]=g0i; u[6]=g1r; u[7]=g1i;
}

// load one 8-complex column (16B-aligned, contiguous) into registers
__device__ __forceinline__ void load_col(const float2* __restrict__ p, float2 dst[8]){
    const float4* q = (const float4*)p;
    #pragma unroll
    for (int h = 0; h < 4; ++h) {
        float4 f = q[h];
        dst[2*h]   = make_float2(f.x, f.y);
        dst[2*h+1] = make_float2(f.z, f.w);
    }
}

__launch_bounds__(128)
__global__ void qmps_kernel(const float* __restrict__ inputs,
                            const float* __restrict__ params,
                            float* __restrict__ out)
{
    __shared__ __align__(16) float2 U[3][NQ][2][2];     // U[l][q] = Rot(params[l+1,q])
    __shared__ __align__(16) float2 v[NQ][2];           // Rot(params[0,q])*RY(x_q)|0>
    __shared__ __align__(16) float2 wc[14][2][8][10];   // wc[slot][m][col][k] = W_m[k][col]
    __shared__ __align__(16) float2 B0s[2][8];
    __shared__ __align__(16) float2 r15s[8][2];
    __shared__ __align__(16) float2 XL[2][8][10];       // LamL staging for merge

    const int t    = threadIdx.x;         // two waves
    const int b    = blockIdx.x;          // batch element
    const int wv   = t >> 6;              // 0 = left env, 1 = right env
    const int lane = t & 63;

    // ---- phase 0: gate matrices (wave0) + init vectors (wave1), parallel ----
    if (t < 48) {
        int l = t >> 4, q = t & 15;
        float u[8]; make_rot(params, l+1, q, u);
        U[l][q][0][0] = make_float2(u[0],u[1]); U[l][q][0][1] = make_float2(u[2],u[3]);
        U[l][q][1][0] = make_float2(u[4],u[5]); U[l][q][1][1] = make_float2(u[6],u[7]);
    } else if (t >= 64 && t < 80) {
        int q = t - 64;
        float u[8]; make_rot(params, 0, q, u);
        fuse_ry(inputs[b*NQ + q], u);
        v[q][0] = make_float2(u[0],u[1]);
        v[q][1] = make_float2(u[4],u[5]);
    }
    __syncthreads();

    // ---- phase 1: site tensors (14 slots x 128 entries, 1 slot per kk) + edges ----
    #pragma unroll 2
    for (int kk = 0; kk < 14; ++kk) {
        int ws    = kk;                   // slot (uniform across block)
        int alpha = t & 7, beta = (t >> 3) & 7, m = (t >> 6) & 1;
        int site  = ws + 1;               // 1..14
        int uu = (site <= 7) ? alpha : beta;    // left-bond bits (c1..c3)
        int dd = (site <= 7) ? beta  : alpha;   // right-bond bits (d1..d3)
        int c1 = uu & 1, c2 = (uu >> 1) & 1, c3 = (uu >> 2) & 1;
        int d1 = dd & 1, d2 = (dd >> 1) & 1, d3 = (dd >> 2) & 1;
        float2 val = cmul(U[2][site][m][d3],
                     cmul(U[1][site][d3^c3][d2],
                     cmul(U[0][site][d2^c2][d1], v[site][d1^c1])));
        wc[ws][m][beta][alpha] = val;
    }
    if (t >= 64 && t < 80) {
        // site 0: B0[j][ap] = U3[j,d3] U2[d3,d2] U1[d2,d1] v[d1]
        int t2 = t - 64;
        int jj = t2 >> 3, ap = t2 & 7;
        int d1 = ap & 1, d2 = (ap>>1)&1, d3 = (ap>>2)&1;
        B0s[jj][ap] = cmul(U[2][0][jj][d3],
                      cmul(U[1][0][d3][d2],
                      cmul(U[0][0][d2][d1], v[0][d1])));
    } else if (t >= 80 && t < 96) {
        // site 15: r15[a][k] = sum_s U3[k,s3] U2[s3^c3,s2] U1[s2^c2,s1] v[s1^c1]
        int t2 = t - 80;
        int a = t2 >> 1, k = t2 & 1;
        int c1 = a & 1, c2 = (a>>1)&1, c3 = (a>>2)&1;
        float2 in1[2], in2[2];
        #pragma unroll
        for (int s2 = 0; s2 < 2; ++s2) {
            float2 acc = make_float2(0.f, 0.f);
            #pragma unroll
            for (int s1 = 0; s1 < 2; ++s1) cfma(acc, U[0][15][s2^c2][s1], v[15][s1^c1]);
            in1[s2] = acc;
        }
        #pragma unroll
        for (int s3 = 0; s3 < 2; ++s3) {
            float2 acc = make_float2(0.f, 0.f);
            #pragma unroll
            for (int s2 = 0; s2 < 2; ++s2) cfma(acc, U[1][15][s3^c3][s2], in1[s2]);
            in2[s3] = acc;
        }
        float2 acc = make_float2(0.f, 0.f);
        #pragma unroll
        for (int s3 = 0; s3 < 2; ++s3) cfma(acc, U[2][15][k][s3], in2[s3]);
        r15s[a][k] = acc;
    }
    __syncthreads();

    const int i = lane >> 3, j = lane & 7;     // lane owns element [i][j]

    // ---- env init (wave-uniform branch) ----
    float2 L0, L1;
    if (wv == 0) {
        L0 = cmulc(B0s[0][i], B0s[0][j]);
        float2 l1 = cmulc(B0s[1][i], B0s[1][j]);
        L1 = make_float2(-l1.x, -l1.y);              // z_1 = -1
    } else {
        float2 r = cmulc(r15s[i][0], r15s[j][0]);
        cfmac(r, r15s[i][1], r15s[j][1]);
        L0 = r; L1 = r;                              // c-independent base
    }

    const int iA0 = (lane & 0x38) << 2;   // row-broadcast base: srclane (i<<3)|k
    const int jB0 = (lane & 7) << 2;      // col-gather base:    srclane (k<<3)|j

    #pragma unroll
    for (int st = 0; st < 7; ++st) {
        const int slot = wv ? (13 - st) : st;   // wave-uniform
        float2 W1[2][8], W2[2][8];
        #pragma unroll
        for (int m = 0; m < 2; ++m) {
            load_col(&wc[slot][m][j][0], W1[m]);   // W_m[k][j]  (stage-1 B-op)
            load_col(&wc[slot][m][i][0], W2[m]);   // W_m[k][i]  (stage-2 A-op)
        }
        // ---- stage 1: P_{c,m}[i][j] = sum_k Lam_c[i][k] * W_m[k][j] ----
        float2 P00 = make_float2(0.f,0.f), P01 = make_float2(0.f,0.f);
        float2 P10 = make_float2(0.f,0.f), P11 = make_float2(0.f,0.f);
        #pragma unroll
        for (int k = 0; k < 8; ++k) {
            const int iA = iA0 | (k << 2);
            float2 a0 = shfl2(L0, iA);
            float2 a1 = shfl2(L1, iA);
            cfma(P00, a0, W1[0][k]); cfma(P01, a0, W1[1][k]);
            cfma(P10, a1, W1[0][k]); cfma(P11, a1, W1[1][k]);
        }
        // ---- stage 2: Lam'_0 = W0^dag P00 + W1^dag P11 ; Lam'_1 = W1^dag P01 + W0^dag P10 ----
        float2 n0 = make_float2(0.f,0.f), n1 = make_float2(0.f,0.f);
        #pragma unroll
        for (int k = 0; k < 8; ++k) {
            const int iB = jB0 | (k << 5);
            float2 p00 = shfl2(P00, iB);
            float2 p01 = shfl2(P01, iB);
            float2 p10 = shfl2(P10, iB);
            float2 p11 = shfl2(P11, iB);
            cfmac(n0, W2[0][k], p00); cfmac(n0, W2[1][k], p11);
            cfmac(n1, W2[1][k], p01); cfmac(n1, W2[0][k], p10);
        }
        L0 = n0; L1 = n1;
    }

    // ---- merge: wave0 publishes LamL; wave1 computes M = Re sum_c <LamL_c . LamR_c> ----
    if (wv == 0) {
        XL[0][i][j] = L0;
        XL[1][i][j] = L1;
    }
    __syncthreads();
    if (wv == 1) {
        float2 A0 = XL[0][i][j];
        float2 A1 = XL[1][i][j];
        float m = A0.x*L0.x - A0.y*L0.y
                + A1.x*L1.x - A1.y*L1.y;
        #pragma unroll
        for (int off = 32; off > 0; off >>= 1) m += __shfl_down(m, off, 64);
        if (lane == 0) out[b] = m;
    }
}

extern "C" void kernel_launch(void* const* d_in, const int* in_sizes, int n_in,
                              void* d_out, int out_size, void* d_ws, size_t ws_size,
                              hipStream_t stream) {
    (void)n_in; (void)out_size; (void)d_ws; (void)ws_size;
    const float* inputs = (const float*)d_in[0];   // (B,16) f32
    const float* params = (const float*)d_in[1];   // (4,16,3) f32
    float* out = (float*)d_out;                    // (B,) f32
    const int B = in_sizes[0] / NQ;
    qmps_kernel<<<B, 128, 0, stream>>>(inputs, params, out);
}